// Round 9
// baseline (158.038 us; speedup 1.0000x reference)
//
#include <hip/hip_runtime.h>
#include <hip/hip_bf16.h>

// MoCo loss on MI355X. V=2, N=1024, D=128, K=65536, fp32 in, 2 fp32 scalars out.
// Round 9: fuse conv+intra+loss1 into one dispatch (block-range partition);
// queue kernel at SUB=8 (1024 blocks, 4/CU) now that epilogue is atomic-free.
//
// loss2 row sums: den += exp(-c), num += c*exp(-c), c = 2-2*dot.
// Partials store raw (Se, Sde); reduce computes den=E, num=2*(E-D).
//
// ws floats:
//   [0,2048)        QS_e[1024], QS_ce[1024]
//   [2048,6144)     IS_e[2][1024] @2048, IS_ce[2][1024] @4096
//   [6144,8192)     l1part[2048]
//   [8192,139264)   QPart[64][2][1024]   slot = xcd*8+sub
//   [139264,172032) IPart[16][2][1024]   slot = x*8+yg
//   byte 2 MB+:     Bblk (bf16, 16 MB)
//
// MFMA 16x16x32 bf16 layouts: A[m=lane&15][k=quad*8+j]; B[k=quad*8+j][n=lane&15];
// C: col=lane&15, row=quad*4+reg.

#define NROWS 1024
#define DDIM  128
#define KQ    65536
#define NTILE 4096          // 65536/16 col-tiles
#define SLICE 512           // tiles per XCD slice (512*4KB = 2MB)
#define SUB   8             // sub-slices -> 8*16*8 = 1024 blocks (4/CU)
#define QPART 8192
#define IPART 139264
#define BBLK_BYTE_OFF (2u*1024u*1024u)
#define TWO_LOG2E 2.8853900817779268f

typedef __attribute__((ext_vector_type(8))) short  short8;
typedef __attribute__((ext_vector_type(4))) float  float4v;

#if __has_builtin(__builtin_amdgcn_exp2f)
#define EXP2(x) __builtin_amdgcn_exp2f(x)
#else
#define EXP2(x) __expf((x) * 0.6931471805599453f)
#endif

__device__ __forceinline__ unsigned short f2bf(float f) {
  unsigned u = __float_as_uint(f);
  u += 0x7FFF + ((u >> 16) & 1);           // RNE
  return (unsigned short)(u >> 16);
}

__device__ __forceinline__ short8 cvt8(const float* __restrict__ p) {
  float4 a = *(const float4*)p;
  float4 b = *(const float4*)(p + 4);
  short8 r;
  r[0] = (short)f2bf(a.x); r[1] = (short)f2bf(a.y);
  r[2] = (short)f2bf(a.z); r[3] = (short)f2bf(a.w);
  r[4] = (short)f2bf(b.x); r[5] = (short)f2bf(b.y);
  r[6] = (short)f2bf(b.z); r[7] = (short)f2bf(b.w);
  return r;
}

__device__ __forceinline__ float wave_sum(float v) {
  #pragma unroll
  for (int o = 32; o > 0; o >>= 1) v += __shfl_down(v, o, 64);
  return v;
}

__global__ void zero_ws(float* __restrict__ ws) {
  ws[blockIdx.x * 256 + threadIdx.x] = 0.f;   // fallback only
}

// ---------- fused pre-pass: conv [0,1024) | intra [1024,1280) | loss1 [1280,1312)
__global__ __launch_bounds__(256) void fused_pre(
    const float* __restrict__ q, const float* __restrict__ kin,
    const float* __restrict__ queue, unsigned short* __restrict__ Bblk,
    float* __restrict__ ws, int doConv) {
  __shared__ float l_e[4][64], l_de[4][64];
  const int b    = (int)blockIdx.x;
  const int tid  = (int)threadIdx.x;
  const int lane = tid & 63;
  const int wave = tid >> 6;

  if (b < 1024) {
    // ---- conv unit b: 64 cols x 128 d, slice = b&7 (XCD-local)
    if (!doConv) return;
    const int xcd  = b & 7;
    const int idx  = b >> 3;
    const int g    = tid >> 4;
    const int ci   = (tid & 15) * 4;
    const int c    = xcd * (SLICE * 16) + idx * 64 + ci;
    const int d0   = g * 8;
    const int kk   = g >> 2;
    const int quad = g & 3;
    float4v v[8];
    #pragma unroll
    for (int dd = 0; dd < 8; ++dd)
      v[dd] = __builtin_nontemporal_load(
          (const float4v*)(queue + (size_t)(d0 + dd) * KQ + c));
    #pragma unroll
    for (int n = 0; n < 4; ++n) {
      int cc = c + n;
      unsigned short* outp = Bblk + ((size_t)(cc >> 4) * 4 + kk) * 512
                                  + (quad * 16 + (cc & 15)) * 8;
      short8 s;
      #pragma unroll
      for (int dd = 0; dd < 8; ++dd)
        s[dd] = (short)f2bf(v[dd][n]);
      *(short8*)outp = s;
    }
  } else if (b < 1280) {
    // ---- intra: idx = rowblk | yg<<4 | x<<7
    const int idx = b - 1024;
    const int rowblk = idx & 15;
    const int yg = (idx >> 4) & 7;
    const int x  = idx >> 7;
    const float* qx = q + (size_t)x * NROWS * DDIM;
    const int quad = lane >> 4;
    const int m    = lane & 15;
    const int rowBase = rowblk * 64;

    short8 a[4][4];
    #pragma unroll
    for (int rg = 0; rg < 4; ++rg)
      #pragma unroll
      for (int kk = 0; kk < 4; ++kk)
        a[rg][kk] = cvt8(qx + (size_t)(rowBase + rg * 16 + m) * DDIM + kk * 32 + quad * 8);

    float ae[4][4] = {}, ade[4][4] = {};
    for (int jt = yg * 4 + wave; jt < NROWS / 16; jt += 32) {
      short8 bfr[4];
      #pragma unroll
      for (int kk = 0; kk < 4; ++kk)
        bfr[kk] = cvt8(qx + (size_t)(jt * 16 + m) * DDIM + kk * 32 + quad * 8);
      const int dgRg = (jt * 16 - rowBase) >> 4;
      #pragma unroll
      for (int rg = 0; rg < 4; ++rg) {
        float4v C = {0.f, 0.f, 0.f, 0.f};
        #pragma unroll
        for (int kk = 0; kk < 4; ++kk)
          C = __builtin_amdgcn_mfma_f32_16x16x32_bf16(a[rg][kk], bfr[kk], C, 0, 0, 0);
        #pragma unroll
        for (int r = 0; r < 4; ++r) {
          float d = C[r];
          float e = EXP2(fmaf(d, TWO_LOG2E, -TWO_LOG2E));
          float de = d * e;
          if (rg == dgRg && (quad * 4 + r) == m) { e = 0.f; de = 0.f; }
          ae[rg][r] += e;
          ade[rg][r] += de;
        }
      }
    }
    #pragma unroll
    for (int rg = 0; rg < 4; ++rg)
      #pragma unroll
      for (int r = 0; r < 4; ++r) {
        float e = ae[rg][r], de = ade[rg][r];
        #pragma unroll
        for (int mk = 8; mk >= 1; mk >>= 1) {
          e  += __shfl_xor(e,  mk, 64);
          de += __shfl_xor(de, mk, 64);
        }
        if (m == 0) {
          l_e[wave][rg * 16 + quad * 4 + r]  = e;
          l_de[wave][rg * 16 + quad * 4 + r] = de;
        }
      }
    __syncthreads();
    if (tid < 64) {
      float E = l_e[0][tid] + l_e[1][tid] + l_e[2][tid] + l_e[3][tid];
      float D = l_de[0][tid] + l_de[1][tid] + l_de[2][tid] + l_de[3][tid];
      const int slot = x * 8 + yg;
      ws[IPART + (size_t)slot * 2048 + rowBase + tid]        = E;
      ws[IPART + (size_t)slot * 2048 + 1024 + rowBase + tid] = D;
    }
  } else {
    // ---- loss1: wave handles 16 (x,i) rows; store raw dot to l1part
    const int gw0 = (b - 1280) * 4 + wave;     // 0..127
    for (int t = 0; t < 16; ++t) {
      const int idx = gw0 * 16 + t;            // 0..2047
      const int x = idx >> 10;
      const int i = idx & 1023;
      const float2* qp = (const float2*)(q + (size_t)(x * NROWS + i) * DDIM);
      const float2* kp = (const float2*)(kin + (size_t)((1 - x) * NROWS + i) * DDIM);
      float2 av = qp[lane];
      float2 bv = kp[lane];
      float s = wave_sum(av.x * bv.x + av.y * bv.y);
      if (lane == 0) ws[6144 + idx] = s;
    }
  }
}

// ---------- queue GEMM: fb: xcd = fb&7, t = fb>>3: rowblk = t&15, sub = t>>4
__global__ __launch_bounds__(256) void mfma_queue_sw(
    const float* __restrict__ q, const unsigned short* __restrict__ Bblk,
    float* __restrict__ ws) {
  const int fb     = (int)blockIdx.x;
  const int xcd    = fb & 7;
  const int t      = fb >> 3;
  const int rowBase = (t & 15) * 64;
  const int sub    = t >> 4;
  const int lane = (int)threadIdx.x & 63;
  const int wave = (int)threadIdx.x >> 6;
  const int quad = lane >> 4;
  const int m    = lane & 15;

  __shared__ float l_e[4][64], l_de[4][64];

  short8 a[4][4];
  #pragma unroll
  for (int rg = 0; rg < 4; ++rg)
    #pragma unroll
    for (int kk = 0; kk < 4; ++kk)
      a[rg][kk] = cvt8(q + (size_t)(rowBase + rg * 16 + m) * DDIM + kk * 32 + quad * 8);

  float ae[4][4] = {}, ade[4][4] = {};

  int wt = xcd * SLICE + sub * 4 + wave;
  const int wtEnd = (xcd + 1) * SLICE;
  short8 bc[4];
  {
    const unsigned short* bp = Bblk + (size_t)wt * 2048 + lane * 8;
    #pragma unroll
    for (int kk = 0; kk < 4; ++kk) bc[kk] = *(const short8*)(bp + kk * 512);
  }
  while (true) {
    const int wtn = wt + SUB * 4;
    const bool more = wtn < wtEnd;
    short8 bn[4];
    if (more) {
      const unsigned short* bp = Bblk + (size_t)wtn * 2048 + lane * 8;
      #pragma unroll
      for (int kk = 0; kk < 4; ++kk) bn[kk] = *(const short8*)(bp + kk * 512);
    }
    #pragma unroll
    for (int rg = 0; rg < 4; ++rg) {
      float4v C = {0.f, 0.f, 0.f, 0.f};
      #pragma unroll
      for (int kk = 0; kk < 4; ++kk)
        C = __builtin_amdgcn_mfma_f32_16x16x32_bf16(a[rg][kk], bc[kk], C, 0, 0, 0);
      #pragma unroll
      for (int r = 0; r < 4; ++r) {
        float d = C[r];
        float e = EXP2(fmaf(d, TWO_LOG2E, -TWO_LOG2E));
        ae[rg][r] += e;
        ade[rg][r] = fmaf(d, e, ade[rg][r]);
      }
    }
    if (!more) break;
    wt = wtn;
    #pragma unroll
    for (int kk = 0; kk < 4; ++kk) bc[kk] = bn[kk];
  }

  #pragma unroll
  for (int rg = 0; rg < 4; ++rg)
    #pragma unroll
    for (int r = 0; r < 4; ++r) {
      float e = ae[rg][r], de = ade[rg][r];
      #pragma unroll
      for (int mk = 8; mk >= 1; mk >>= 1) {
        e  += __shfl_xor(e,  mk, 64);
        de += __shfl_xor(de, mk, 64);
      }
      if (m == 0) {
        l_e[wave][rg * 16 + quad * 4 + r]  = e;
        l_de[wave][rg * 16 + quad * 4 + r] = de;
      }
    }
  __syncthreads();
  const int tid = (int)threadIdx.x;
  if (tid < 64) {
    float E = l_e[0][tid] + l_e[1][tid] + l_e[2][tid] + l_e[3][tid];
    float D = l_de[0][tid] + l_de[1][tid] + l_de[2][tid] + l_de[3][tid];
    const int slot = xcd * SUB + sub;
    ws[QPART + (size_t)slot * 2048 + rowBase + tid]        = E;
    ws[QPART + (size_t)slot * 2048 + 1024 + rowBase + tid] = D;
  }
}

// ---------- chunked fallback (ws too small for full Bblk) ----------

__global__ void conv_B_ck(const float* __restrict__ queue,
                          unsigned short* __restrict__ Bblk, int c0chunk) {
  const int tid  = (int)threadIdx.x;
  const int g    = tid >> 4;
  const int ci   = (tid & 15) * 4;
  const int cloc = (int)blockIdx.x * 64 + ci;
  const int c    = c0chunk + cloc;
  const int d0   = g * 8;
  const int kk   = g >> 2;
  const int quad = g & 3;
  float4v v[8];
  #pragma unroll
  for (int dd = 0; dd < 8; ++dd)
    v[dd] = *(const float4v*)(queue + (size_t)(d0 + dd) * KQ + c);
  unsigned short* outp = Bblk + ((size_t)(cloc >> 4) * 4 + kk) * 512
                              + (quad * 16 + (cloc & 15)) * 8;
  #pragma unroll
  for (int n = 0; n < 4; ++n) {
    short8 s;
    #pragma unroll
    for (int dd = 0; dd < 8; ++dd)
      s[dd] = (short)f2bf(v[dd][n]);
    *(short8*)(outp + n * 8) = s;
  }
}

__global__ __launch_bounds__(256) void mfma_queue_ck(
    const float* __restrict__ q, const unsigned short* __restrict__ Bblk,
    int cnt, float* __restrict__ acc_e, float* __restrict__ acc_ce) {
  const int lane = (int)threadIdx.x & 63;
  const int wave = (int)threadIdx.x >> 6;
  const int quad = lane >> 4;
  const int m    = lane & 15;
  const int rowBase = (int)blockIdx.x * 64;

  short8 a[4][4];
  #pragma unroll
  for (int rg = 0; rg < 4; ++rg)
    #pragma unroll
    for (int kk = 0; kk < 4; ++kk)
      a[rg][kk] = cvt8(q + (size_t)(rowBase + rg * 16 + m) * DDIM + kk * 32 + quad * 8);

  float ae[4][4] = {}, ade[4][4] = {};
  const int stride = (int)gridDim.y * 4;
  int wt = (int)blockIdx.y * 4 + wave;
  if (wt < cnt) {
    short8 bc[4];
    {
      const unsigned short* bp = Bblk + (size_t)wt * 2048 + lane * 8;
      #pragma unroll
      for (int kk = 0; kk < 4; ++kk) bc[kk] = *(const short8*)(bp + kk * 512);
    }
    while (true) {
      const int wtn = wt + stride;
      const bool more = wtn < cnt;
      short8 bn[4];
      if (more) {
        const unsigned short* bp = Bblk + (size_t)wtn * 2048 + lane * 8;
        #pragma unroll
        for (int kk = 0; kk < 4; ++kk) bn[kk] = *(const short8*)(bp + kk * 512);
      }
      #pragma unroll
      for (int rg = 0; rg < 4; ++rg) {
        float4v C = {0.f, 0.f, 0.f, 0.f};
        #pragma unroll
        for (int kk = 0; kk < 4; ++kk)
          C = __builtin_amdgcn_mfma_f32_16x16x32_bf16(a[rg][kk], bc[kk], C, 0, 0, 0);
        #pragma unroll
        for (int r = 0; r < 4; ++r) {
          float d = C[r];
          float e = EXP2(fmaf(d, TWO_LOG2E, -TWO_LOG2E));
          ae[rg][r] += e;
          ade[rg][r] = fmaf(d, e, ade[rg][r]);
        }
      }
      if (!more) break;
      wt = wtn;
      #pragma unroll
      for (int kk = 0; kk < 4; ++kk) bc[kk] = bn[kk];
    }
  }
  #pragma unroll
  for (int rg = 0; rg < 4; ++rg)
    #pragma unroll
    for (int r = 0; r < 4; ++r) {
      float e = ae[rg][r], de = ade[rg][r];
      #pragma unroll
      for (int mk = 8; mk >= 1; mk >>= 1) {
        e  += __shfl_xor(e,  mk, 64);
        de += __shfl_xor(de, mk, 64);
      }
      if (m == 0) {
        int row = rowBase + rg * 16 + quad * 4 + r;
        atomicAdd(&acc_e[row],  e);
        atomicAdd(&acc_ce[row], 2.f * (e - de));
      }
    }
}

// reduce partials -> QS/IS. 12 blocks: 0-3 queue rows (if doQ), 4-11 intra.
__global__ void reduce_k(float* __restrict__ ws, int doQ) {
  const int b = (int)blockIdx.x;
  const int t = (int)threadIdx.x;
  if (b < 4) {
    if (!doQ) return;
    const int row = b * 256 + t;
    float E = 0.f, D = 0.f;
    #pragma unroll 4
    for (int s = 0; s < 8 * SUB; ++s) {
      E += ws[QPART + (size_t)s * 2048 + row];
      D += ws[QPART + (size_t)s * 2048 + 1024 + row];
    }
    ws[row]        = E;
    ws[1024 + row] = 2.f * (E - D);
  } else {
    const int idx = (b - 4) * 256 + t;
    const int x   = idx >> 10;
    const int row = idx & 1023;
    float E = 0.f, D = 0.f;
    #pragma unroll
    for (int g = 0; g < 8; ++g) {
      const int s = x * 8 + g;
      E += ws[IPART + (size_t)s * 2048 + row];
      D += ws[IPART + (size_t)s * 2048 + 1024 + row];
    }
    ws[2048 + x * 1024 + row] = E;
    ws[4096 + x * 1024 + row] = 2.f * (E - D);
  }
}

// final: loss2 assembly + loss1 partial fold, single block.
__global__ void final_k(const float* __restrict__ ws, float* __restrict__ out) {
  const float* QS_e   = ws;
  const float* QS_ce  = ws + 1024;
  const float* IS_e   = ws + 2048;
  const float* IS_ce  = ws + 4096;
  const float* l1part = ws + 6144;
  __shared__ float red1[256], red2[256];
  float p1 = 0.f, p2 = 0.f;
  for (int idx = (int)threadIdx.x; idx < 2048; idx += 256) {
    int x = idx >> 10;
    int i = idx & 1023;
    p1 += 2.f - 2.f * l1part[idx];
    float den = QS_e[i] + IS_e[x * 1024 + i];
    float num = QS_ce[i] + IS_ce[x * 1024 + i];
    p2 += num / den;
  }
  red1[threadIdx.x] = p1;
  red2[threadIdx.x] = p2;
  __syncthreads();
  for (int s = 128; s > 0; s >>= 1) {
    if ((int)threadIdx.x < s) {
      red1[threadIdx.x] += red1[threadIdx.x + s];
      red2[threadIdx.x] += red2[threadIdx.x + s];
    }
    __syncthreads();
  }
  if (threadIdx.x == 0) {
    out[0] = red1[0] * (1.f / (2.f * NROWS));
    out[1] = -red2[0] * (1.f / (2.f * NROWS));
  }
}

extern "C" void kernel_launch(void* const* d_in, const int* in_sizes, int n_in,
                              void* d_out, int out_size, void* d_ws, size_t ws_size,
                              hipStream_t stream) {
  const float* q     = (const float*)d_in[0];   // [2][1024][128]
  const float* k     = (const float*)d_in[1];   // [2][1024][128]
  const float* queue = (const float*)d_in[2];   // [128][65536]
  float* ws  = (float*)d_ws;
  float* out = (float*)d_out;
  unsigned short* Bblk = (unsigned short*)((char*)d_ws + BBLK_BYTE_OFF);

  const size_t needFull = BBLK_BYTE_OFF + (size_t)NTILE * 4096;   // 2MB hdr + 16MB
  if (ws_size >= needFull) {
    hipLaunchKernelGGL(fused_pre, dim3(1312), dim3(256), 0, stream,
                       q, k, queue, Bblk, ws, 1);
    hipLaunchKernelGGL(mfma_queue_sw, dim3(8 * 16 * SUB), dim3(256), 0, stream,
                       q, Bblk, ws);
    hipLaunchKernelGGL(reduce_k, dim3(12), dim3(256), 0, stream, ws, 1);
  } else {
    // fallback: intra+loss1 via fused_pre (conv blocks no-op), chunked queue
    hipLaunchKernelGGL(zero_ws, dim3(8), dim3(256), 0, stream, ws);
    hipLaunchKernelGGL(fused_pre, dim3(1312), dim3(256), 0, stream,
                       q, k, queue, Bblk, ws, 0);
    size_t avail = (ws_size > BBLK_BYTE_OFF) ? (ws_size - BBLK_BYTE_OFF) : 16384;
    int maxJt = (int)(avail / 4096);
    maxJt &= ~3;
    if (maxJt > NTILE) maxJt = NTILE;
    if (maxJt < 4) maxJt = 4;
    int nch = (NTILE + maxJt - 1) / maxJt;
    for (int c = 0; c < nch; ++c) {
      int jt0  = c * maxJt;
      int cntc = NTILE - jt0; if (cntc > maxJt) cntc = maxJt;
      hipLaunchKernelGGL(conv_B_ck, dim3(cntc / 4), dim3(256), 0, stream,
                         queue, Bblk, jt0 * 16);
      int gy = (cntc + 3) / 4; if (gy > 64) gy = 64;
      hipLaunchKernelGGL(mfma_queue_ck, dim3(16, gy), dim3(256), 0, stream,
                         q, Bblk, cntc, ws, ws + 1024);
    }
    hipLaunchKernelGGL(reduce_k, dim3(12), dim3(256), 0, stream, ws, 0);
  }

  hipLaunchKernelGGL(final_k, dim3(1), dim3(256), 0, stream, ws, out);
}

// Round 10
// 146.556 us; speedup vs baseline: 1.0783x; 1.0783x over previous
//
#include <hip/hip_runtime.h>
#include <hip/hip_bf16.h>

// MoCo loss on MI355X. V=2, N=1024, D=128, K=65536, fp32 in, 2 fp32 scalars out.
// Round 10: revert R9 fusion (regressed); queue kernel re-tiled to 32-row
// blocks (2 rg) to cut VGPR/wave (~160 -> ~100) and lift the register-capped
// occupancy that R9 proved was the limiter (2x blocks, same 18% occ).
//
// loss2 row sums: den += exp(-c), num += c*exp(-c), c = 2-2*dot.
// Partials store raw (Se, Sde); reduce computes den=E, num=2*(E-D).
//
// ws floats:
//   [0,2048)       QS_e[1024], QS_ce[1024]
//   [2048,6144)    IS_e[2][1024] @2048, IS_ce[2][1024] @4096
//   [6144,8192)    l1part[2048]
//   [8192,73728)   QPart[32][2][1024]   slot = xcd*SUB+sub
//   [73728,106496) IPart[16][2][1024]   slot = x*8+yg
//   byte 2 MB+:    Bblk (bf16, 16 MB)
//
// MFMA 16x16x32 bf16 layouts: A[m=lane&15][k=quad*8+j]; B[k=quad*8+j][n=lane&15];
// C: col=lane&15, row=quad*4+reg.

#define NROWS 1024
#define DDIM  128
#define KQ    65536
#define NTILE 4096          // 65536/16 col-tiles
#define SLICE 512           // tiles per XCD slice (512*4KB = 2MB)
#define SUB   4             // sub-slices -> 8 xcd * 32 rowblk * 4 = 4096 blocks
#define QPART 8192
#define IPART 73728
#define BBLK_BYTE_OFF (2u*1024u*1024u)
#define TWO_LOG2E 2.8853900817779268f

typedef __attribute__((ext_vector_type(8))) short  short8;
typedef __attribute__((ext_vector_type(4))) float  float4v;

#if __has_builtin(__builtin_amdgcn_exp2f)
#define EXP2(x) __builtin_amdgcn_exp2f(x)
#else
#define EXP2(x) __expf((x) * 0.6931471805599453f)
#endif

__device__ __forceinline__ unsigned short f2bf(float f) {
  unsigned u = __float_as_uint(f);
  u += 0x7FFF + ((u >> 16) & 1);           // RNE
  return (unsigned short)(u >> 16);
}

__device__ __forceinline__ short8 cvt8(const float* __restrict__ p) {
  float4 a = *(const float4*)p;
  float4 b = *(const float4*)(p + 4);
  short8 r;
  r[0] = (short)f2bf(a.x); r[1] = (short)f2bf(a.y);
  r[2] = (short)f2bf(a.z); r[3] = (short)f2bf(a.w);
  r[4] = (short)f2bf(b.x); r[5] = (short)f2bf(b.y);
  r[6] = (short)f2bf(b.z); r[7] = (short)f2bf(b.w);
  return r;
}

__device__ __forceinline__ float wave_sum(float v) {
  #pragma unroll
  for (int o = 32; o > 0; o >>= 1) v += __shfl_down(v, o, 64);
  return v;
}

__global__ void zero_ws(float* __restrict__ ws) {
  ws[blockIdx.x * 256 + threadIdx.x] = 0.f;   // fallback only
}

// ---------- conv: queue [128][65536] fp32 -> Bblk tiles (4KB), XCD-sliced ----

__global__ void conv_B_sw(const float* __restrict__ queue,
                          unsigned short* __restrict__ Bblk) {
  const int fb   = (int)blockIdx.x;
  const int xcd  = fb & 7;
  const int idx  = fb >> 3;                       // 0..127 within slice
  const int tid  = (int)threadIdx.x;
  const int g    = tid >> 4;                      // 0..15 -> d0 = g*8
  const int ci   = (tid & 15) * 4;
  const int c    = xcd * (SLICE * 16) + idx * 64 + ci;   // global col
  const int d0   = g * 8;
  const int kk   = g >> 2;
  const int quad = g & 3;

  float4v v[8];
  #pragma unroll
  for (int dd = 0; dd < 8; ++dd)
    v[dd] = __builtin_nontemporal_load(
        (const float4v*)(queue + (size_t)(d0 + dd) * KQ + c));

  #pragma unroll
  for (int n = 0; n < 4; ++n) {
    int cc = c + n;
    unsigned short* outp = Bblk + ((size_t)(cc >> 4) * 4 + kk) * 512
                                + (quad * 16 + (cc & 15)) * 8;
    short8 s;
    #pragma unroll
    for (int dd = 0; dd < 8; ++dd)
      s[dd] = (short)f2bf(v[dd][n]);
    *(short8*)outp = s;
  }
}

// ---------- queue GEMM: 32-row blocks. fb: xcd=fb&7, t=fb>>3: rowblk=t&31, sub=t>>5
__global__ __launch_bounds__(256) void mfma_queue_sw(
    const float* __restrict__ q, const unsigned short* __restrict__ Bblk,
    float* __restrict__ ws) {
  const int fb      = (int)blockIdx.x;
  const int xcd     = fb & 7;
  const int t       = fb >> 3;
  const int rowBase = (t & 31) * 32;
  const int sub     = t >> 5;                    // 0..SUB-1
  const int lane = (int)threadIdx.x & 63;
  const int wave = (int)threadIdx.x >> 6;
  const int quad = lane >> 4;
  const int m    = lane & 15;

  __shared__ float l_e[4][32], l_de[4][32];

  short8 a[2][4];
  #pragma unroll
  for (int rg = 0; rg < 2; ++rg)
    #pragma unroll
    for (int kk = 0; kk < 4; ++kk)
      a[rg][kk] = cvt8(q + (size_t)(rowBase + rg * 16 + m) * DDIM + kk * 32 + quad * 8);

  float ae[2][4] = {}, ade[2][4] = {};

  int wt = xcd * SLICE + sub * 4 + wave;
  const int wtEnd = (xcd + 1) * SLICE;
  short8 bc[4];
  {
    const unsigned short* bp = Bblk + (size_t)wt * 2048 + lane * 8;
    #pragma unroll
    for (int kk = 0; kk < 4; ++kk) bc[kk] = *(const short8*)(bp + kk * 512);
  }
  while (true) {
    const int wtn = wt + SUB * 4;
    const bool more = wtn < wtEnd;
    short8 bn[4];
    if (more) {
      const unsigned short* bp = Bblk + (size_t)wtn * 2048 + lane * 8;
      #pragma unroll
      for (int kk = 0; kk < 4; ++kk) bn[kk] = *(const short8*)(bp + kk * 512);
    }
    #pragma unroll
    for (int rg = 0; rg < 2; ++rg) {
      float4v C = {0.f, 0.f, 0.f, 0.f};
      #pragma unroll
      for (int kk = 0; kk < 4; ++kk)
        C = __builtin_amdgcn_mfma_f32_16x16x32_bf16(a[rg][kk], bc[kk], C, 0, 0, 0);
      #pragma unroll
      for (int r = 0; r < 4; ++r) {
        float d = C[r];
        float e = EXP2(fmaf(d, TWO_LOG2E, -TWO_LOG2E));
        ae[rg][r] += e;
        ade[rg][r] = fmaf(d, e, ade[rg][r]);
      }
    }
    if (!more) break;
    wt = wtn;
    #pragma unroll
    for (int kk = 0; kk < 4; ++kk) bc[kk] = bn[kk];
  }

  #pragma unroll
  for (int rg = 0; rg < 2; ++rg)
    #pragma unroll
    for (int r = 0; r < 4; ++r) {
      float e = ae[rg][r], de = ade[rg][r];
      #pragma unroll
      for (int mk = 8; mk >= 1; mk >>= 1) {
        e  += __shfl_xor(e,  mk, 64);
        de += __shfl_xor(de, mk, 64);
      }
      if (m == 0) {
        l_e[wave][rg * 16 + quad * 4 + r]  = e;
        l_de[wave][rg * 16 + quad * 4 + r] = de;
      }
    }
  __syncthreads();
  const int tid = (int)threadIdx.x;
  if (tid < 32) {
    float E = l_e[0][tid] + l_e[1][tid] + l_e[2][tid] + l_e[3][tid];
    float D = l_de[0][tid] + l_de[1][tid] + l_de[2][tid] + l_de[3][tid];
    const int slot = xcd * SUB + sub;
    ws[QPART + (size_t)slot * 2048 + rowBase + tid]        = E;
    ws[QPART + (size_t)slot * 2048 + 1024 + rowBase + tid] = D;
  }
}

// ---------- chunked fallback (ws too small for full Bblk) ----------

__global__ void conv_B_ck(const float* __restrict__ queue,
                          unsigned short* __restrict__ Bblk, int c0chunk) {
  const int tid  = (int)threadIdx.x;
  const int g    = tid >> 4;
  const int ci   = (tid & 15) * 4;
  const int cloc = (int)blockIdx.x * 64 + ci;
  const int c    = c0chunk + cloc;
  const int d0   = g * 8;
  const int kk   = g >> 2;
  const int quad = g & 3;
  float4v v[8];
  #pragma unroll
  for (int dd = 0; dd < 8; ++dd)
    v[dd] = *(const float4v*)(queue + (size_t)(d0 + dd) * KQ + c);
  unsigned short* outp = Bblk + ((size_t)(cloc >> 4) * 4 + kk) * 512
                              + (quad * 16 + (cloc & 15)) * 8;
  #pragma unroll
  for (int n = 0; n < 4; ++n) {
    short8 s;
    #pragma unroll
    for (int dd = 0; dd < 8; ++dd)
      s[dd] = (short)f2bf(v[dd][n]);
    *(short8*)(outp + n * 8) = s;
  }
}

__global__ __launch_bounds__(256) void mfma_queue_ck(
    const float* __restrict__ q, const unsigned short* __restrict__ Bblk,
    int cnt, float* __restrict__ acc_e, float* __restrict__ acc_ce) {
  const int lane = (int)threadIdx.x & 63;
  const int wave = (int)threadIdx.x >> 6;
  const int quad = lane >> 4;
  const int m    = lane & 15;
  const int rowBase = (int)blockIdx.x * 64;

  short8 a[4][4];
  #pragma unroll
  for (int rg = 0; rg < 4; ++rg)
    #pragma unroll
    for (int kk = 0; kk < 4; ++kk)
      a[rg][kk] = cvt8(q + (size_t)(rowBase + rg * 16 + m) * DDIM + kk * 32 + quad * 8);

  float ae[4][4] = {}, ade[4][4] = {};
  const int stride = (int)gridDim.y * 4;
  int wt = (int)blockIdx.y * 4 + wave;
  if (wt < cnt) {
    short8 bc[4];
    {
      const unsigned short* bp = Bblk + (size_t)wt * 2048 + lane * 8;
      #pragma unroll
      for (int kk = 0; kk < 4; ++kk) bc[kk] = *(const short8*)(bp + kk * 512);
    }
    while (true) {
      const int wtn = wt + stride;
      const bool more = wtn < cnt;
      short8 bn[4];
      if (more) {
        const unsigned short* bp = Bblk + (size_t)wtn * 2048 + lane * 8;
        #pragma unroll
        for (int kk = 0; kk < 4; ++kk) bn[kk] = *(const short8*)(bp + kk * 512);
      }
      #pragma unroll
      for (int rg = 0; rg < 4; ++rg) {
        float4v C = {0.f, 0.f, 0.f, 0.f};
        #pragma unroll
        for (int kk = 0; kk < 4; ++kk)
          C = __builtin_amdgcn_mfma_f32_16x16x32_bf16(a[rg][kk], bc[kk], C, 0, 0, 0);
        #pragma unroll
        for (int r = 0; r < 4; ++r) {
          float d = C[r];
          float e = EXP2(fmaf(d, TWO_LOG2E, -TWO_LOG2E));
          ae[rg][r] += e;
          ade[rg][r] = fmaf(d, e, ade[rg][r]);
        }
      }
      if (!more) break;
      wt = wtn;
      #pragma unroll
      for (int kk = 0; kk < 4; ++kk) bc[kk] = bn[kk];
    }
  }
  #pragma unroll
  for (int rg = 0; rg < 4; ++rg)
    #pragma unroll
    for (int r = 0; r < 4; ++r) {
      float e = ae[rg][r], de = ade[rg][r];
      #pragma unroll
      for (int mk = 8; mk >= 1; mk >>= 1) {
        e  += __shfl_xor(e,  mk, 64);
        de += __shfl_xor(de, mk, 64);
      }
      if (m == 0) {
        int row = rowBase + rg * 16 + quad * 4 + r;
        atomicAdd(&acc_e[row],  e);
        atomicAdd(&acc_ce[row], 2.f * (e - de));
      }
    }
}

// ---------- intra: 256 blocks (rowblk x yg x view), direct store ----------

__global__ __launch_bounds__(256) void mfma_intra(
    const float* __restrict__ q, float* __restrict__ ws) {
  const int x  = (int)blockIdx.z;
  const int yg = (int)blockIdx.y;
  const float* qx = q + (size_t)x * NROWS * DDIM;
  const int lane = (int)threadIdx.x & 63;
  const int wave = (int)threadIdx.x >> 6;
  const int quad = lane >> 4;
  const int m    = lane & 15;
  const int rowBase = (int)blockIdx.x * 64;

  __shared__ float l_e[4][64], l_de[4][64];

  short8 a[4][4];
  #pragma unroll
  for (int rg = 0; rg < 4; ++rg)
    #pragma unroll
    for (int kk = 0; kk < 4; ++kk)
      a[rg][kk] = cvt8(qx + (size_t)(rowBase + rg * 16 + m) * DDIM + kk * 32 + quad * 8);

  float ae[4][4] = {}, ade[4][4] = {};

  for (int jt = yg * 4 + wave; jt < NROWS / 16; jt += 32) {
    short8 b[4];
    #pragma unroll
    for (int kk = 0; kk < 4; ++kk)
      b[kk] = cvt8(qx + (size_t)(jt * 16 + m) * DDIM + kk * 32 + quad * 8);
    const int dgRg = (jt * 16 - rowBase) >> 4;
    #pragma unroll
    for (int rg = 0; rg < 4; ++rg) {
      float4v C = {0.f, 0.f, 0.f, 0.f};
      #pragma unroll
      for (int kk = 0; kk < 4; ++kk)
        C = __builtin_amdgcn_mfma_f32_16x16x32_bf16(a[rg][kk], b[kk], C, 0, 0, 0);
      #pragma unroll
      for (int r = 0; r < 4; ++r) {
        float d = C[r];
        float e = EXP2(fmaf(d, TWO_LOG2E, -TWO_LOG2E));
        float de = d * e;
        if (rg == dgRg && (quad * 4 + r) == m) { e = 0.f; de = 0.f; }
        ae[rg][r] += e;
        ade[rg][r] += de;
      }
    }
  }

  #pragma unroll
  for (int rg = 0; rg < 4; ++rg)
    #pragma unroll
    for (int r = 0; r < 4; ++r) {
      float e = ae[rg][r], de = ade[rg][r];
      #pragma unroll
      for (int mk = 8; mk >= 1; mk >>= 1) {
        e  += __shfl_xor(e,  mk, 64);
        de += __shfl_xor(de, mk, 64);
      }
      if (m == 0) {
        l_e[wave][rg * 16 + quad * 4 + r]  = e;
        l_de[wave][rg * 16 + quad * 4 + r] = de;
      }
    }
  __syncthreads();
  const int tid = (int)threadIdx.x;
  if (tid < 64) {
    float E = l_e[0][tid] + l_e[1][tid] + l_e[2][tid] + l_e[3][tid];
    float D = l_de[0][tid] + l_de[1][tid] + l_de[2][tid] + l_de[3][tid];
    const int slot = x * 8 + yg;
    ws[IPART + (size_t)slot * 2048 + rowBase + tid]        = E;
    ws[IPART + (size_t)slot * 2048 + 1024 + rowBase + tid] = D;
  }
}

// reduce partials -> QS/IS. 12 blocks: 0-3 queue rows (if doQ), 4-11 intra.
__global__ void reduce_k(float* __restrict__ ws, int doQ) {
  const int b = (int)blockIdx.x;
  const int t = (int)threadIdx.x;
  if (b < 4) {
    if (!doQ) return;
    const int row = b * 256 + t;
    float E = 0.f, D = 0.f;
    #pragma unroll 4
    for (int s = 0; s < 8 * SUB; ++s) {
      E += ws[QPART + (size_t)s * 2048 + row];
      D += ws[QPART + (size_t)s * 2048 + 1024 + row];
    }
    ws[row]        = E;
    ws[1024 + row] = 2.f * (E - D);
  } else {
    const int idx = (b - 4) * 256 + t;
    const int x   = idx >> 10;
    const int row = idx & 1023;
    float E = 0.f, D = 0.f;
    #pragma unroll
    for (int g = 0; g < 8; ++g) {
      const int s = x * 8 + g;
      E += ws[IPART + (size_t)s * 2048 + row];
      D += ws[IPART + (size_t)s * 2048 + 1024 + row];
    }
    ws[2048 + x * 1024 + row] = E;
    ws[4096 + x * 1024 + row] = 2.f * (E - D);
  }
}

// loss1: one wave per (x,i); store raw dot (no atomics).
__global__ void loss1_k(const float* __restrict__ q, const float* __restrict__ k,
                        float* __restrict__ l1part) {
  int gw   = (int)(blockIdx.x * blockDim.x + threadIdx.x) >> 6;   // 0..2047
  int lane = (int)threadIdx.x & 63;
  int x = gw >> 10;
  int i = gw & 1023;
  const float2* qp = (const float2*)(q + (size_t)(x * NROWS + i) * DDIM);
  const float2* kp = (const float2*)(k + (size_t)((1 - x) * NROWS + i) * DDIM);
  float2 a = qp[lane];
  float2 b = kp[lane];
  float s = wave_sum(a.x * b.x + a.y * b.y);
  if (lane == 0) l1part[gw] = s;
}

// final: loss2 assembly + loss1 partial fold, single block.
__global__ void final_k(const float* __restrict__ ws, float* __restrict__ out) {
  const float* QS_e   = ws;
  const float* QS_ce  = ws + 1024;
  const float* IS_e   = ws + 2048;
  const float* IS_ce  = ws + 4096;
  const float* l1part = ws + 6144;
  __shared__ float red1[256], red2[256];
  float p1 = 0.f, p2 = 0.f;
  for (int idx = (int)threadIdx.x; idx < 2048; idx += 256) {
    int x = idx >> 10;
    int i = idx & 1023;
    p1 += 2.f - 2.f * l1part[idx];
    float den = QS_e[i] + IS_e[x * 1024 + i];
    float num = QS_ce[i] + IS_ce[x * 1024 + i];
    p2 += num / den;
  }
  red1[threadIdx.x] = p1;
  red2[threadIdx.x] = p2;
  __syncthreads();
  for (int s = 128; s > 0; s >>= 1) {
    if ((int)threadIdx.x < s) {
      red1[threadIdx.x] += red1[threadIdx.x + s];
      red2[threadIdx.x] += red2[threadIdx.x + s];
    }
    __syncthreads();
  }
  if (threadIdx.x == 0) {
    out[0] = red1[0] * (1.f / (2.f * NROWS));
    out[1] = -red2[0] * (1.f / (2.f * NROWS));
  }
}

extern "C" void kernel_launch(void* const* d_in, const int* in_sizes, int n_in,
                              void* d_out, int out_size, void* d_ws, size_t ws_size,
                              hipStream_t stream) {
  const float* q     = (const float*)d_in[0];   // [2][1024][128]
  const float* k     = (const float*)d_in[1];   // [2][1024][128]
  const float* queue = (const float*)d_in[2];   // [128][65536]
  float* ws  = (float*)d_ws;
  float* out = (float*)d_out;
  unsigned short* Bblk = (unsigned short*)((char*)d_ws + BBLK_BYTE_OFF);

  const size_t needFull = BBLK_BYTE_OFF + (size_t)NTILE * 4096;   // 2MB hdr + 16MB
  if (ws_size >= needFull) {
    hipLaunchKernelGGL(conv_B_sw, dim3(1024), dim3(256), 0, stream, queue, Bblk);
    hipLaunchKernelGGL(mfma_intra, dim3(16, 8, 2), dim3(256), 0, stream, q, ws);
    hipLaunchKernelGGL(loss1_k, dim3(512), dim3(256), 0, stream, q, k, ws + 6144);
    hipLaunchKernelGGL(mfma_queue_sw, dim3(8 * 32 * SUB), dim3(256), 0, stream,
                       q, Bblk, ws);
    hipLaunchKernelGGL(reduce_k, dim3(12), dim3(256), 0, stream, ws, 1);
  } else {
    // fallback: chunked queue path with atomics into QS (zeroed first)
    unsigned short* Bsmall = (unsigned short*)((char*)d_ws + 512 * 1024);
    hipLaunchKernelGGL(zero_ws, dim3(8), dim3(256), 0, stream, ws);
    hipLaunchKernelGGL(mfma_intra, dim3(16, 8, 2), dim3(256), 0, stream, q, ws);
    hipLaunchKernelGGL(loss1_k, dim3(512), dim3(256), 0, stream, q, k, ws + 6144);
    size_t avail = (ws_size > 512 * 1024) ? (ws_size - 512 * 1024) : 16384;
    int maxJt = (int)(avail / 4096);
    maxJt &= ~3;
    if (maxJt > NTILE) maxJt = NTILE;
    if (maxJt < 4) maxJt = 4;
    int nch = (NTILE + maxJt - 1) / maxJt;
    for (int c = 0; c < nch; ++c) {
      int jt0  = c * maxJt;
      int cntc = NTILE - jt0; if (cntc > maxJt) cntc = maxJt;
      hipLaunchKernelGGL(conv_B_ck, dim3(cntc / 4), dim3(256), 0, stream,
                         queue, Bsmall, jt0 * 16);
      int gy = (cntc + 3) / 4; if (gy > 64) gy = 64;
      hipLaunchKernelGGL(mfma_queue_ck, dim3(16, gy), dim3(256), 0, stream,
                         q, Bsmall, cntc, ws, ws + 1024);
    }
    hipLaunchKernelGGL(reduce_k, dim3(12), dim3(256), 0, stream, ws, 0);
  }

  hipLaunchKernelGGL(final_k, dim3(1), dim3(256), 0, stream, ws, out);
}

// Round 11
// 141.984 us; speedup vs baseline: 1.1131x; 1.0322x over previous
//
#include <hip/hip_runtime.h>
#include <hip/hip_bf16.h>

// MoCo loss on MI355X. V=2, N=1024, D=128, K=65536, fp32 in, 2 fp32 scalars out.
// Round 11: mega-dispatch AFTER conv: intra(2-rg) + loss1 + queue(2-rg) in one
// kernel (block-range partition, all ~100 VGPR class). Queue blocks start
// right behind 544 small blocks; intra/loss1 hide in queue's L2-latency slack.
// Unlike R9's failed fusion, conv stays separate (producer) and queue is not
// delayed behind heavy blocks.
//
// loss2 row sums: den += exp(-c), num += c*exp(-c), c = 2-2*dot.
// Partials store raw (Se, Sde); reduce computes den=E, num=2*(E-D).
//
// ws floats:
//   [0,2048)       QS_e[1024], QS_ce[1024]
//   [2048,6144)    IS_e[2][1024] @2048, IS_ce[2][1024] @4096
//   [6144,8192)    l1part[2048]
//   [8192,73728)   QPart[32][2][1024]   slot = xcd*SUB+sub
//   [73728,106496) IPart[16][2][1024]   slot = x*8+yg
//   byte 2 MB+:    Bblk (bf16, 16 MB)
//
// MFMA 16x16x32 bf16 layouts: A[m=lane&15][k=quad*8+j]; B[k=quad*8+j][n=lane&15];
// C: col=lane&15, row=quad*4+reg.

#define NROWS 1024
#define DDIM  128
#define KQ    65536
#define NTILE 4096          // 65536/16 col-tiles
#define SLICE 512           // tiles per XCD slice (512*4KB = 2MB)
#define SUB   4
#define QPART 8192
#define IPART 73728
#define BBLK_BYTE_OFF (2u*1024u*1024u)
#define TWO_LOG2E 2.8853900817779268f

// mega-dispatch block ranges (queue offset must be 0 mod 8 for XCD swizzle)
#define MB_INTRA 512
#define MB_L1    544
#define MB_TOTAL (MB_L1 + 8 * 32 * SUB)   // 544 + 4096 = 4640

typedef __attribute__((ext_vector_type(8))) short  short8;
typedef __attribute__((ext_vector_type(4))) float  float4v;

#if __has_builtin(__builtin_amdgcn_exp2f)
#define EXP2(x) __builtin_amdgcn_exp2f(x)
#else
#define EXP2(x) __expf((x) * 0.6931471805599453f)
#endif

__device__ __forceinline__ unsigned short f2bf(float f) {
  unsigned u = __float_as_uint(f);
  u += 0x7FFF + ((u >> 16) & 1);           // RNE
  return (unsigned short)(u >> 16);
}

__device__ __forceinline__ short8 cvt8(const float* __restrict__ p) {
  float4 a = *(const float4*)p;
  float4 b = *(const float4*)(p + 4);
  short8 r;
  r[0] = (short)f2bf(a.x); r[1] = (short)f2bf(a.y);
  r[2] = (short)f2bf(a.z); r[3] = (short)f2bf(a.w);
  r[4] = (short)f2bf(b.x); r[5] = (short)f2bf(b.y);
  r[6] = (short)f2bf(b.z); r[7] = (short)f2bf(b.w);
  return r;
}

__device__ __forceinline__ float wave_sum(float v) {
  #pragma unroll
  for (int o = 32; o > 0; o >>= 1) v += __shfl_down(v, o, 64);
  return v;
}

__global__ void zero_ws(float* __restrict__ ws) {
  ws[blockIdx.x * 256 + threadIdx.x] = 0.f;   // fallback only
}

// ---------- conv: queue [128][65536] fp32 -> Bblk tiles (4KB), XCD-sliced ----

__global__ void conv_B_sw(const float* __restrict__ queue,
                          unsigned short* __restrict__ Bblk) {
  const int fb   = (int)blockIdx.x;
  const int xcd  = fb & 7;
  const int idx  = fb >> 3;                       // 0..127 within slice
  const int tid  = (int)threadIdx.x;
  const int g    = tid >> 4;                      // 0..15 -> d0 = g*8
  const int ci   = (tid & 15) * 4;
  const int c    = xcd * (SLICE * 16) + idx * 64 + ci;   // global col
  const int d0   = g * 8;
  const int kk   = g >> 2;
  const int quad = g & 3;

  float4v v[8];
  #pragma unroll
  for (int dd = 0; dd < 8; ++dd)
    v[dd] = __builtin_nontemporal_load(
        (const float4v*)(queue + (size_t)(d0 + dd) * KQ + c));

  #pragma unroll
  for (int n = 0; n < 4; ++n) {
    int cc = c + n;
    unsigned short* outp = Bblk + ((size_t)(cc >> 4) * 4 + kk) * 512
                                + (quad * 16 + (cc & 15)) * 8;
    short8 s;
    #pragma unroll
    for (int dd = 0; dd < 8; ++dd)
      s[dd] = (short)f2bf(v[dd][n]);
    *(short8*)outp = s;
  }
}

// ---------- mega: intra [0,512) | loss1 [512,544) | queue [544,4640) --------

__global__ __launch_bounds__(256) void mega_k(
    const float* __restrict__ q, const float* __restrict__ kin,
    const unsigned short* __restrict__ Bblk, float* __restrict__ ws) {
  __shared__ float l_e[4][32], l_de[4][32];
  const int b    = (int)blockIdx.x;
  const int tid  = (int)threadIdx.x;
  const int lane = tid & 63;
  const int wave = tid >> 6;
  const int quad = lane >> 4;
  const int m    = lane & 15;

  if (b >= MB_L1) {
    // ---- queue GEMM: 32-row blocks, XCD-sliced B reuse
    const int fb      = b - MB_L1;                // 544 % 8 == 0 keeps swizzle
    const int xcd     = fb & 7;
    const int t       = fb >> 3;
    const int rowBase = (t & 31) * 32;
    const int sub     = t >> 5;                   // 0..SUB-1

    short8 a[2][4];
    #pragma unroll
    for (int rg = 0; rg < 2; ++rg)
      #pragma unroll
      for (int kk = 0; kk < 4; ++kk)
        a[rg][kk] = cvt8(q + (size_t)(rowBase + rg * 16 + m) * DDIM + kk * 32 + quad * 8);

    float ae[2][4] = {}, ade[2][4] = {};

    int wt = xcd * SLICE + sub * 4 + wave;
    const int wtEnd = (xcd + 1) * SLICE;
    short8 bc[4];
    {
      const unsigned short* bp = Bblk + (size_t)wt * 2048 + lane * 8;
      #pragma unroll
      for (int kk = 0; kk < 4; ++kk) bc[kk] = *(const short8*)(bp + kk * 512);
    }
    while (true) {
      const int wtn = wt + SUB * 4;
      const bool more = wtn < wtEnd;
      short8 bn[4];
      if (more) {
        const unsigned short* bp = Bblk + (size_t)wtn * 2048 + lane * 8;
        #pragma unroll
        for (int kk = 0; kk < 4; ++kk) bn[kk] = *(const short8*)(bp + kk * 512);
      }
      #pragma unroll
      for (int rg = 0; rg < 2; ++rg) {
        float4v C = {0.f, 0.f, 0.f, 0.f};
        #pragma unroll
        for (int kk = 0; kk < 4; ++kk)
          C = __builtin_amdgcn_mfma_f32_16x16x32_bf16(a[rg][kk], bc[kk], C, 0, 0, 0);
        #pragma unroll
        for (int r = 0; r < 4; ++r) {
          float d = C[r];
          float e = EXP2(fmaf(d, TWO_LOG2E, -TWO_LOG2E));
          ae[rg][r] += e;
          ade[rg][r] = fmaf(d, e, ade[rg][r]);
        }
      }
      if (!more) break;
      wt = wtn;
      #pragma unroll
      for (int kk = 0; kk < 4; ++kk) bc[kk] = bn[kk];
    }

    #pragma unroll
    for (int rg = 0; rg < 2; ++rg)
      #pragma unroll
      for (int r = 0; r < 4; ++r) {
        float e = ae[rg][r], de = ade[rg][r];
        #pragma unroll
        for (int mk = 8; mk >= 1; mk >>= 1) {
          e  += __shfl_xor(e,  mk, 64);
          de += __shfl_xor(de, mk, 64);
        }
        if (m == 0) {
          l_e[wave][rg * 16 + quad * 4 + r]  = e;
          l_de[wave][rg * 16 + quad * 4 + r] = de;
        }
      }
    __syncthreads();
    if (tid < 32) {
      float E = l_e[0][tid] + l_e[1][tid] + l_e[2][tid] + l_e[3][tid];
      float D = l_de[0][tid] + l_de[1][tid] + l_de[2][tid] + l_de[3][tid];
      const int slot = xcd * SUB + sub;
      ws[QPART + (size_t)slot * 2048 + rowBase + tid]        = E;
      ws[QPART + (size_t)slot * 2048 + 1024 + rowBase + tid] = D;
    }
  } else if (b < MB_INTRA) {
    // ---- intra 2-rg: b = rowblk | yg<<5 | x<<8
    const int rowblk = b & 31;
    const int yg = (b >> 5) & 7;
    const int x  = b >> 8;
    const float* qx = q + (size_t)x * NROWS * DDIM;
    const int rowBase = rowblk * 32;

    short8 a[2][4];
    #pragma unroll
    for (int rg = 0; rg < 2; ++rg)
      #pragma unroll
      for (int kk = 0; kk < 4; ++kk)
        a[rg][kk] = cvt8(qx + (size_t)(rowBase + rg * 16 + m) * DDIM + kk * 32 + quad * 8);

    float ae[2][4] = {}, ade[2][4] = {};
    for (int jt = yg * 4 + wave; jt < NROWS / 16; jt += 32) {
      short8 bfr[4];
      #pragma unroll
      for (int kk = 0; kk < 4; ++kk)
        bfr[kk] = cvt8(qx + (size_t)(jt * 16 + m) * DDIM + kk * 32 + quad * 8);
      const int dgRg = (jt * 16 - rowBase) >> 4;   // 0..1 iff tile hits diagonal
      #pragma unroll
      for (int rg = 0; rg < 2; ++rg) {
        float4v C = {0.f, 0.f, 0.f, 0.f};
        #pragma unroll
        for (int kk = 0; kk < 4; ++kk)
          C = __builtin_amdgcn_mfma_f32_16x16x32_bf16(a[rg][kk], bfr[kk], C, 0, 0, 0);
        #pragma unroll
        for (int r = 0; r < 4; ++r) {
          float d = C[r];
          float e = EXP2(fmaf(d, TWO_LOG2E, -TWO_LOG2E));
          float de = d * e;
          if (rg == dgRg && (quad * 4 + r) == m) { e = 0.f; de = 0.f; }
          ae[rg][r] += e;
          ade[rg][r] += de;
        }
      }
    }
    #pragma unroll
    for (int rg = 0; rg < 2; ++rg)
      #pragma unroll
      for (int r = 0; r < 4; ++r) {
        float e = ae[rg][r], de = ade[rg][r];
        #pragma unroll
        for (int mk = 8; mk >= 1; mk >>= 1) {
          e  += __shfl_xor(e,  mk, 64);
          de += __shfl_xor(de, mk, 64);
        }
        if (m == 0) {
          l_e[wave][rg * 16 + quad * 4 + r]  = e;
          l_de[wave][rg * 16 + quad * 4 + r] = de;
        }
      }
    __syncthreads();
    if (tid < 32) {
      float E = l_e[0][tid] + l_e[1][tid] + l_e[2][tid] + l_e[3][tid];
      float D = l_de[0][tid] + l_de[1][tid] + l_de[2][tid] + l_de[3][tid];
      const int slot = x * 8 + yg;
      ws[IPART + (size_t)slot * 2048 + rowBase + tid]        = E;
      ws[IPART + (size_t)slot * 2048 + 1024 + rowBase + tid] = D;
    }
  } else {
    // ---- loss1: wave handles 16 (x,i) rows; store raw dot (no atomics)
    const int gw0 = (b - MB_INTRA) * 4 + wave;   // 0..127
    for (int t = 0; t < 16; ++t) {
      const int idx = gw0 * 16 + t;              // 0..2047
      const int x = idx >> 10;
      const int i = idx & 1023;
      const float2* qp = (const float2*)(q + (size_t)(x * NROWS + i) * DDIM);
      const float2* kp = (const float2*)(kin + (size_t)((1 - x) * NROWS + i) * DDIM);
      float2 av = qp[lane];
      float2 bv = kp[lane];
      float s = wave_sum(av.x * bv.x + av.y * bv.y);
      if (lane == 0) ws[6144 + idx] = s;
    }
  }
}

// ---------- chunked fallback (ws too small for full Bblk) ----------

__global__ void conv_B_ck(const float* __restrict__ queue,
                          unsigned short* __restrict__ Bblk, int c0chunk) {
  const int tid  = (int)threadIdx.x;
  const int g    = tid >> 4;
  const int ci   = (tid & 15) * 4;
  const int cloc = (int)blockIdx.x * 64 + ci;
  const int c    = c0chunk + cloc;
  const int d0   = g * 8;
  const int kk   = g >> 2;
  const int quad = g & 3;
  float4v v[8];
  #pragma unroll
  for (int dd = 0; dd < 8; ++dd)
    v[dd] = *(const float4v*)(queue + (size_t)(d0 + dd) * KQ + c);
  unsigned short* outp = Bblk + ((size_t)(cloc >> 4) * 4 + kk) * 512
                              + (quad * 16 + (cloc & 15)) * 8;
  #pragma unroll
  for (int n = 0; n < 4; ++n) {
    short8 s;
    #pragma unroll
    for (int dd = 0; dd < 8; ++dd)
      s[dd] = (short)f2bf(v[dd][n]);
    *(short8*)(outp + n * 8) = s;
  }
}

__global__ __launch_bounds__(256) void mfma_queue_ck(
    const float* __restrict__ q, const unsigned short* __restrict__ Bblk,
    int cnt, float* __restrict__ acc_e, float* __restrict__ acc_ce) {
  const int lane = (int)threadIdx.x & 63;
  const int wave = (int)threadIdx.x >> 6;
  const int quad = lane >> 4;
  const int m    = lane & 15;
  const int rowBase = (int)blockIdx.x * 64;

  short8 a[4][4];
  #pragma unroll
  for (int rg = 0; rg < 4; ++rg)
    #pragma unroll
    for (int kk = 0; kk < 4; ++kk)
      a[rg][kk] = cvt8(q + (size_t)(rowBase + rg * 16 + m) * DDIM + kk * 32 + quad * 8);

  float ae[4][4] = {}, ade[4][4] = {};
  const int stride = (int)gridDim.y * 4;
  int wt = (int)blockIdx.y * 4 + wave;
  if (wt < cnt) {
    short8 bc[4];
    {
      const unsigned short* bp = Bblk + (size_t)wt * 2048 + lane * 8;
      #pragma unroll
      for (int kk = 0; kk < 4; ++kk) bc[kk] = *(const short8*)(bp + kk * 512);
    }
    while (true) {
      const int wtn = wt + stride;
      const bool more = wtn < cnt;
      short8 bn[4];
      if (more) {
        const unsigned short* bp = Bblk + (size_t)wtn * 2048 + lane * 8;
        #pragma unroll
        for (int kk = 0; kk < 4; ++kk) bn[kk] = *(const short8*)(bp + kk * 512);
      }
      #pragma unroll
      for (int rg = 0; rg < 4; ++rg) {
        float4v C = {0.f, 0.f, 0.f, 0.f};
        #pragma unroll
        for (int kk = 0; kk < 4; ++kk)
          C = __builtin_amdgcn_mfma_f32_16x16x32_bf16(a[rg][kk], bc[kk], C, 0, 0, 0);
        #pragma unroll
        for (int r = 0; r < 4; ++r) {
          float d = C[r];
          float e = EXP2(fmaf(d, TWO_LOG2E, -TWO_LOG2E));
          ae[rg][r] += e;
          ade[rg][r] = fmaf(d, e, ade[rg][r]);
        }
      }
      if (!more) break;
      wt = wtn;
      #pragma unroll
      for (int kk = 0; kk < 4; ++kk) bc[kk] = bn[kk];
    }
  }
  #pragma unroll
  for (int rg = 0; rg < 4; ++rg)
    #pragma unroll
    for (int r = 0; r < 4; ++r) {
      float e = ae[rg][r], de = ade[rg][r];
      #pragma unroll
      for (int mk = 8; mk >= 1; mk >>= 1) {
        e  += __shfl_xor(e,  mk, 64);
        de += __shfl_xor(de, mk, 64);
      }
      if (m == 0) {
        int row = rowBase + rg * 16 + quad * 4 + r;
        atomicAdd(&acc_e[row],  e);
        atomicAdd(&acc_ce[row], 2.f * (e - de));
      }
    }
}

// fallback intra (4-rg) + loss1
__global__ __launch_bounds__(256) void mfma_intra(
    const float* __restrict__ q, float* __restrict__ ws) {
  const int x  = (int)blockIdx.z;
  const int yg = (int)blockIdx.y;
  const float* qx = q + (size_t)x * NROWS * DDIM;
  const int lane = (int)threadIdx.x & 63;
  const int wave = (int)threadIdx.x >> 6;
  const int quad = lane >> 4;
  const int m    = lane & 15;
  const int rowBase = (int)blockIdx.x * 64;

  __shared__ float l_e[4][64], l_de[4][64];

  short8 a[4][4];
  #pragma unroll
  for (int rg = 0; rg < 4; ++rg)
    #pragma unroll
    for (int kk = 0; kk < 4; ++kk)
      a[rg][kk] = cvt8(qx + (size_t)(rowBase + rg * 16 + m) * DDIM + kk * 32 + quad * 8);

  float ae[4][4] = {}, ade[4][4] = {};
  for (int jt = yg * 4 + wave; jt < NROWS / 16; jt += 32) {
    short8 bfr[4];
    #pragma unroll
    for (int kk = 0; kk < 4; ++kk)
      bfr[kk] = cvt8(qx + (size_t)(jt * 16 + m) * DDIM + kk * 32 + quad * 8);
    const int dgRg = (jt * 16 - rowBase) >> 4;
    #pragma unroll
    for (int rg = 0; rg < 4; ++rg) {
      float4v C = {0.f, 0.f, 0.f, 0.f};
      #pragma unroll
      for (int kk = 0; kk < 4; ++kk)
        C = __builtin_amdgcn_mfma_f32_16x16x32_bf16(a[rg][kk], bfr[kk], C, 0, 0, 0);
      #pragma unroll
      for (int r = 0; r < 4; ++r) {
        float d = C[r];
        float e = EXP2(fmaf(d, TWO_LOG2E, -TWO_LOG2E));
        float de = d * e;
        if (rg == dgRg && (quad * 4 + r) == m) { e = 0.f; de = 0.f; }
        ae[rg][r] += e;
        ade[rg][r] += de;
      }
    }
  }
  #pragma unroll
  for (int rg = 0; rg < 4; ++rg)
    #pragma unroll
    for (int r = 0; r < 4; ++r) {
      float e = ae[rg][r], de = ade[rg][r];
      #pragma unroll
      for (int mk = 8; mk >= 1; mk >>= 1) {
        e  += __shfl_xor(e,  mk, 64);
        de += __shfl_xor(de, mk, 64);
      }
      if (m == 0) {
        l_e[wave][rg * 16 + quad * 4 + r]  = e;
        l_de[wave][rg * 16 + quad * 4 + r] = de;
      }
    }
  __syncthreads();
  const int tid = (int)threadIdx.x;
  if (tid < 64) {
    float E = l_e[0][tid] + l_e[1][tid] + l_e[2][tid] + l_e[3][tid];
    float D = l_de[0][tid] + l_de[1][tid] + l_de[2][tid] + l_de[3][tid];
    const int slot = x * 8 + yg;
    ws[IPART + (size_t)slot * 2048 + rowBase + tid]        = E;
    ws[IPART + (size_t)slot * 2048 + 1024 + rowBase + tid] = D;
  }
}

__global__ void loss1_k(const float* __restrict__ q, const float* __restrict__ k,
                        float* __restrict__ l1part) {
  int gw   = (int)(blockIdx.x * blockDim.x + threadIdx.x) >> 6;
  int lane = (int)threadIdx.x & 63;
  int x = gw >> 10;
  int i = gw & 1023;
  const float2* qp = (const float2*)(q + (size_t)(x * NROWS + i) * DDIM);
  const float2* kp = (const float2*)(k + (size_t)((1 - x) * NROWS + i) * DDIM);
  float2 a = qp[lane];
  float2 b = kp[lane];
  float s = wave_sum(a.x * b.x + a.y * b.y);
  if (lane == 0) l1part[gw] = s;
}

// reduce partials -> QS/IS. 12 blocks: 0-3 queue rows (if doQ), 4-11 intra.
__global__ void reduce_k(float* __restrict__ ws, int doQ) {
  const int b = (int)blockIdx.x;
  const int t = (int)threadIdx.x;
  if (b < 4) {
    if (!doQ) return;
    const int row = b * 256 + t;
    float E = 0.f, D = 0.f;
    #pragma unroll 4
    for (int s = 0; s < 8 * SUB; ++s) {
      E += ws[QPART + (size_t)s * 2048 + row];
      D += ws[QPART + (size_t)s * 2048 + 1024 + row];
    }
    ws[row]        = E;
    ws[1024 + row] = 2.f * (E - D);
  } else {
    const int idx = (b - 4) * 256 + t;
    const int x   = idx >> 10;
    const int row = idx & 1023;
    float E = 0.f, D = 0.f;
    #pragma unroll
    for (int g = 0; g < 8; ++g) {
      const int s = x * 8 + g;
      E += ws[IPART + (size_t)s * 2048 + row];
      D += ws[IPART + (size_t)s * 2048 + 1024 + row];
    }
    ws[2048 + x * 1024 + row] = E;
    ws[4096 + x * 1024 + row] = 2.f * (E - D);
  }
}

// final: loss2 assembly + loss1 partial fold, single block.
__global__ void final_k(const float* __restrict__ ws, float* __restrict__ out) {
  const float* QS_e   = ws;
  const float* QS_ce  = ws + 1024;
  const float* IS_e   = ws + 2048;
  const float* IS_ce  = ws + 4096;
  const float* l1part = ws + 6144;
  __shared__ float red1[256], red2[256];
  float p1 = 0.f, p2 = 0.f;
  for (int idx = (int)threadIdx.x; idx < 2048; idx += 256) {
    int x = idx >> 10;
    int i = idx & 1023;
    p1 += 2.f - 2.f * l1part[idx];
    float den = QS_e[i] + IS_e[x * 1024 + i];
    float num = QS_ce[i] + IS_ce[x * 1024 + i];
    p2 += num / den;
  }
  red1[threadIdx.x] = p1;
  red2[threadIdx.x] = p2;
  __syncthreads();
  for (int s = 128; s > 0; s >>= 1) {
    if ((int)threadIdx.x < s) {
      red1[threadIdx.x] += red1[threadIdx.x + s];
      red2[threadIdx.x] += red2[threadIdx.x + s];
    }
    __syncthreads();
  }
  if (threadIdx.x == 0) {
    out[0] = red1[0] * (1.f / (2.f * NROWS));
    out[1] = -red2[0] * (1.f / (2.f * NROWS));
  }
}

extern "C" void kernel_launch(void* const* d_in, const int* in_sizes, int n_in,
                              void* d_out, int out_size, void* d_ws, size_t ws_size,
                              hipStream_t stream) {
  const float* q     = (const float*)d_in[0];   // [2][1024][128]
  const float* k     = (const float*)d_in[1];   // [2][1024][128]
  const float* queue = (const float*)d_in[2];   // [128][65536]
  float* ws  = (float*)d_ws;
  float* out = (float*)d_out;
  unsigned short* Bblk = (unsigned short*)((char*)d_ws + BBLK_BYTE_OFF);

  const size_t needFull = BBLK_BYTE_OFF + (size_t)NTILE * 4096;   // 2MB hdr + 16MB
  if (ws_size >= needFull) {
    hipLaunchKernelGGL(conv_B_sw, dim3(1024), dim3(256), 0, stream, queue, Bblk);
    hipLaunchKernelGGL(mega_k, dim3(MB_TOTAL), dim3(256), 0, stream,
                       q, k, Bblk, ws);
    hipLaunchKernelGGL(reduce_k, dim3(12), dim3(256), 0, stream, ws, 1);
  } else {
    // fallback: chunked queue path with atomics into QS (zeroed first)
    unsigned short* Bsmall = (unsigned short*)((char*)d_ws + 512 * 1024);
    hipLaunchKernelGGL(zero_ws, dim3(8), dim3(256), 0, stream, ws);
    hipLaunchKernelGGL(mfma_intra, dim3(16, 8, 2), dim3(256), 0, stream, q, ws);
    hipLaunchKernelGGL(loss1_k, dim3(512), dim3(256), 0, stream, q, k, ws + 6144);
    size_t avail = (ws_size > 512 * 1024) ? (ws_size - 512 * 1024) : 16384;
    int maxJt = (int)(avail / 4096);
    maxJt &= ~3;
    if (maxJt > NTILE) maxJt = NTILE;
    if (maxJt < 4) maxJt = 4;
    int nch = (NTILE + maxJt - 1) / maxJt;
    for (int c = 0; c < nch; ++c) {
      int jt0  = c * maxJt;
      int cntc = NTILE - jt0; if (cntc > maxJt) cntc = maxJt;
      hipLaunchKernelGGL(conv_B_ck, dim3(cntc / 4), dim3(256), 0, stream,
                         queue, Bsmall, jt0 * 16);
      int gy = (cntc + 3) / 4; if (gy > 64) gy = 64;
      hipLaunchKernelGGL(mfma_queue_ck, dim3(16, gy), dim3(256), 0, stream,
                         q, Bsmall, cntc, ws, ws + 1024);
    }
    hipLaunchKernelGGL(reduce_k, dim3(12), dim3(256), 0, stream, ws, 0);
  }

  hipLaunchKernelGGL(final_k, dim3(1), dim3(256), 0, stream, ws, out);
}